// Round 4
// baseline (856.824 us; speedup 1.0000x reference)
//
#include <hip/hip_runtime.h>

#define IMG 512
#define CIN 32
#define COUT 32
#define NORI 8
#define HW (IMG*IMG)

#define TS 16
#define HALO 4
#define WIN 24            // TS + 2*HALO
#define WROW 25           // padded row stride (floats)
#define CBLK 8
#define CHSTRIDE (WIN*WROW)   // 600 floats per channel

// tw layout: tw[((r*9 + k)*CIN + c)*COUT + o]
__global__ void build_tw_kernel(const float* __restrict__ weight, float* __restrict__ tw) {
    int idx = blockIdx.x * blockDim.x + threadIdx.x; // 0..1023
    if (idx >= COUT * CIN) return;
    int o = idx / CIN, c = idx % CIN;
    float b[9];
#pragma unroll
    for (int t = 0; t < 9; ++t) b[t] = weight[(o * CIN + c) * 9 + t];

    float w45[9];
    const float cs = 0.70710678f;
#pragma unroll
    for (int i = 0; i < 3; ++i) {
#pragma unroll
        for (int j = 0; j < 3; ++j) {
            float ys = cs * (float)(i - 1) + cs * (float)(j - 1) + 1.0f;
            float xs = -cs * (float)(i - 1) + cs * (float)(j - 1) + 1.0f;
            float y0f = floorf(ys), x0f = floorf(xs);
            float wy = ys - y0f, wx = xs - x0f;
            int iy0 = (int)y0f, ix0 = (int)x0f;
            float acc = 0.0f;
#pragma unroll
            for (int dy = 0; dy < 2; ++dy) {
#pragma unroll
                for (int dx = 0; dx < 2; ++dx) {
                    int iy = iy0 + dy, ix = ix0 + dx;
                    float wgt = (dy ? wy : 1.0f - wy) * (dx ? wx : 1.0f - wx);
                    bool valid = (iy >= 0) && (iy < 3) && (ix >= 0) && (ix < 3);
                    int iyc = min(max(iy, 0), 2), ixc = min(max(ix, 0), 2);
                    acc += b[iyc * 3 + ixc] * (valid ? wgt : 0.0f);
                }
            }
            w45[i * 3 + j] = acc;
        }
    }

#pragma unroll
    for (int r = 0; r < NORI; ++r) {
        const float* src = (r < 4) ? b : w45;
        int rr = r & 3;
#pragma unroll
        for (int i = 0; i < 3; ++i) {
#pragma unroll
            for (int j = 0; j < 3; ++j) {
                int si, sj;
                if (rr == 0) { si = i;     sj = j;     }
                else if (rr == 1) { si = j;     sj = 2 - i; }
                else if (rr == 2) { si = 2 - i; sj = 2 - j; }
                else { si = 2 - j; sj = i;     }
                tw[(((r * 9) + (i * 3 + j)) * CIN + c) * COUT + o] = src[si * 3 + sj];
            }
        }
    }
}

__global__ __launch_bounds__(256, 2) void fused_deform_kernel(
    const float* __restrict__ x,
    const float* __restrict__ offw, const float* __restrict__ offb,
    const float* __restrict__ mskw, const float* __restrict__ mskb,
    const float* __restrict__ gm,
    const float* __restrict__ tw,
    float* __restrict__ out)
{
    __shared__ float L[CBLK * CHSTRIDE + 64];

    const int tiles_x = IMG / TS;
    int bx = blockIdx.x % tiles_x, by = blockIdx.x / tiles_x;
    int tx = threadIdx.x & 15, ty = threadIdx.x >> 4;
    int X = bx * TS + tx, Y = by * TS + ty;
    int p = Y * IMG + X;
    int y0w = by * TS - HALO, x0w = bx * TS - HALO;

    // ---- phase 1: offset (18ch) + mask (9ch) 3x3 conv, LDS-staged ----
    float acc[27];
#pragma unroll
    for (int i = 0; i < 18; ++i) acc[i] = offb[i];
#pragma unroll
    for (int i = 0; i < 9; ++i) acc[18 + i] = mskb[i];

    for (int cb = 0; cb < 4; ++cb) {
        __syncthreads();
#pragma unroll
        for (int ch = 0; ch < CBLK; ++ch) {
            const float* xc = x + (cb * CBLK + ch) * HW;
            for (int t = threadIdx.x; t < WIN * WIN; t += 256) {
                int rr = t / WIN, cc = t - rr * WIN;
                int gy = y0w + rr, gx = x0w + cc;
                float v = 0.0f;
                if ((unsigned)gy < (unsigned)IMG && (unsigned)gx < (unsigned)IMG)
                    v = xc[gy * IMG + gx];
                L[ch * CHSTRIDE + rr * WROW + cc] = v;
            }
        }
        __syncthreads();

#pragma unroll
        for (int ch = 0; ch < CBLK; ++ch) {
            int c = cb * CBLK + ch;
            int base = ch * CHSTRIDE + (ty + HALO - 1) * WROW + (tx + HALO - 1);
            float v[9];
#pragma unroll
            for (int kyy = 0; kyy < 3; ++kyy) {
                v[kyy * 3 + 0] = L[base + kyy * WROW + 0];
                v[kyy * 3 + 1] = L[base + kyy * WROW + 1];
                v[kyy * 3 + 2] = L[base + kyy * WROW + 2];
            }
            const float* wo = offw + c * 9;   // wave-uniform -> s_load
#pragma unroll
            for (int oc = 0; oc < 18; ++oc) {
#pragma unroll
                for (int t = 0; t < 9; ++t)
                    acc[oc] = fmaf(v[t], wo[oc * CIN * 9 + t], acc[oc]);
            }
            const float* wm = mskw + c * 9;
#pragma unroll
            for (int oc = 0; oc < 9; ++oc) {
#pragma unroll
                for (int t = 0; t < 9; ++t)
                    acc[18 + oc] = fmaf(v[t], wm[oc * CIN * 9 + t], acc[18 + oc]);
            }
        }
    }

    // fixups: offset ch 8,9 = 0 (center tap), mask ch 4 = 0 pre-sigmoid
    acc[8] = 0.0f; acc[9] = 0.0f; acc[22] = 0.0f;
    float modm[9];
#pragma unroll
    for (int i = 0; i < 9; ++i) modm[i] = 1.0f / (1.0f + __expf(-acc[18 + i]));

    // ---- sector from one-hot group_mask ----
    int r = 0;
#pragma unroll
    for (int n = 1; n < NORI; ++n) r = (gm[n * HW + p] > 0.5f) ? n : r;

    // ---- phase 2: deformable sampling (LDS fast path) + GEMV + relu ----
    float oacc[32];
#pragma unroll
    for (int o = 0; o < 32; ++o) oacc[o] = 0.0f;

    for (int cb = 0; cb < 4; ++cb) {
        __syncthreads();
#pragma unroll
        for (int ch = 0; ch < CBLK; ++ch) {
            const float* xc = x + (cb * CBLK + ch) * HW;
            for (int t = threadIdx.x; t < WIN * WIN; t += 256) {
                int rr = t / WIN, cc = t - rr * WIN;
                int gy = y0w + rr, gx = x0w + cc;
                float v = 0.0f;
                if ((unsigned)gy < (unsigned)IMG && (unsigned)gx < (unsigned)IMG)
                    v = xc[gy * IMG + gx];
                L[ch * CHSTRIDE + rr * WROW + cc] = v;
            }
        }
        __syncthreads();

        // k loop MUST stay fully unrolled: runtime-indexed acc[2k]/modm[k]
        // demotes the arrays to scratch (R3: WRITE_SIZE 32MB -> 1.05GB).
#pragma unroll
        for (int k = 0; k < 9; ++k) {
            const int ky = k / 3, kx = k % 3;
            float pyf = (float)(Y - 1 + ky) + acc[2 * k];
            float pxf = (float)(X - 1 + kx) + acc[2 * k + 1];
            float y0f = floorf(pyf), x0f = floorf(pxf);
            float wy = pyf - y0f, wx = pxf - x0f;
            int iy0 = (int)y0f, ix0 = (int)x0f;
            int iy1 = iy0 + 1, ix1 = ix0 + 1;
            float m = modm[k];
            float vy0 = ((unsigned)iy0 < (unsigned)IMG) ? 1.0f : 0.0f;
            float vy1 = ((unsigned)iy1 < (unsigned)IMG) ? 1.0f : 0.0f;
            float vx0 = ((unsigned)ix0 < (unsigned)IMG) ? 1.0f : 0.0f;
            float vx1 = ((unsigned)ix1 < (unsigned)IMG) ? 1.0f : 0.0f;
            int cy0 = min(max(iy0, 0), IMG - 1), cy1 = min(max(iy1, 0), IMG - 1);
            int cx0 = min(max(ix0, 0), IMG - 1), cx1 = min(max(ix1, 0), IMG - 1);
            float w00 = m * (1.0f - wy) * (1.0f - wx) * vy0 * vx0;
            float w01 = m * (1.0f - wy) * wx * vy0 * vx1;
            float w10 = m * wy * (1.0f - wx) * vy1 * vx0;
            float w11 = m * wy * wx * vy1 * vx1;

            int ry0 = cy0 - y0w, rx0 = cx0 - x0w;
            int ry1 = cy1 - y0w, rx1 = cx1 - x0w;
            bool inwin = ((unsigned)ry0 < WIN) && ((unsigned)rx0 < WIN) &&
                         ((unsigned)ry1 < WIN) && ((unsigned)rx1 < WIN);
            const float* twk = tw + ((r * 9 + k) * CIN + cb * CBLK) * COUT;

            if (__all(inwin)) {
                // fast path: index EACH corner by its own clamped coords
                // (negative-side clamping collapses cy0==cy1 / cx0==cx1
                // while the second corner still has nonzero weight).
                int l00 = ry0 * WROW + rx0;
                int l01 = ry0 * WROW + rx1;
                int l10 = ry1 * WROW + rx0;
                int l11 = ry1 * WROW + rx1;
#pragma unroll
                for (int ch = 0; ch < CBLK; ++ch) {
                    int lb = ch * CHSTRIDE;
                    float v00 = L[lb + l00], v01 = L[lb + l01];
                    float v10 = L[lb + l10], v11 = L[lb + l11];
                    float s = fmaf(w00, v00, fmaf(w01, v01, fmaf(w10, v10, w11 * v11)));
                    const float4* t4p = (const float4*)(twk + ch * COUT);
#pragma unroll
                    for (int oq = 0; oq < 8; ++oq) {
                        float4 t4 = t4p[oq];
                        oacc[oq * 4 + 0] = fmaf(s, t4.x, oacc[oq * 4 + 0]);
                        oacc[oq * 4 + 1] = fmaf(s, t4.y, oacc[oq * 4 + 1]);
                        oacc[oq * 4 + 2] = fmaf(s, t4.z, oacc[oq * 4 + 2]);
                        oacc[oq * 4 + 3] = fmaf(s, t4.w, oacc[oq * 4 + 3]);
                    }
                }
            } else {
                // slow path (|offset| >= 3): exact global reads
                int g00 = cy0 * IMG + cx0, g01 = cy0 * IMG + cx1;
                int g10 = cy1 * IMG + cx0, g11 = cy1 * IMG + cx1;
#pragma unroll
                for (int ch = 0; ch < CBLK; ++ch) {
                    const float* xc = x + (cb * CBLK + ch) * HW;
                    float v00 = xc[g00], v01 = xc[g01];
                    float v10 = xc[g10], v11 = xc[g11];
                    float s = fmaf(w00, v00, fmaf(w01, v01, fmaf(w10, v10, w11 * v11)));
                    const float4* t4p = (const float4*)(twk + ch * COUT);
#pragma unroll
                    for (int oq = 0; oq < 8; ++oq) {
                        float4 t4 = t4p[oq];
                        oacc[oq * 4 + 0] = fmaf(s, t4.x, oacc[oq * 4 + 0]);
                        oacc[oq * 4 + 1] = fmaf(s, t4.y, oacc[oq * 4 + 1]);
                        oacc[oq * 4 + 2] = fmaf(s, t4.z, oacc[oq * 4 + 2]);
                        oacc[oq * 4 + 3] = fmaf(s, t4.w, oacc[oq * 4 + 3]);
                    }
                }
            }
        }
    }

#pragma unroll
    for (int o = 0; o < 32; ++o) out[o * HW + p] = fmaxf(oacc[o], 0.0f);
}

extern "C" void kernel_launch(void* const* d_in, const int* in_sizes, int n_in,
                              void* d_out, int out_size, void* d_ws, size_t ws_size,
                              hipStream_t stream) {
    const float* x      = (const float*)d_in[0];
    const float* weight = (const float*)d_in[1];
    const float* offw   = (const float*)d_in[2];
    const float* offb   = (const float*)d_in[3];
    const float* mskw   = (const float*)d_in[4];
    const float* mskb   = (const float*)d_in[5];
    const float* gm     = (const float*)d_in[6];
    float* out = (float*)d_out;
    float* tw  = (float*)d_ws; // 8*9*32*32*4 = 294912 bytes

    build_tw_kernel<<<4, 256, 0, stream>>>(weight, tw);

    const int tiles = (IMG / TS) * (IMG / TS); // 1024 blocks
    fused_deform_kernel<<<tiles, 256, 0, stream>>>(x, offw, offb, mskw, mskb, gm, tw, out);
}

// Round 5
// 505.924 us; speedup vs baseline: 1.6936x; 1.6936x over previous
//
#include <hip/hip_runtime.h>

#define IMG 512
#define CIN 32
#define COUT 32
#define NORI 8
#define HW (IMG*IMG)

#define TS 16

// ---- K1 staging geometry (halo 1) ----
#define W1 18
#define WR1 19
#define CHS1 (W1*WR1)      // 342 floats per channel
#define CB1 16             // channels per stage

// ---- K2 staging geometry (halo 4) ----
#define HALO 4
#define WIN 24
#define WROW 25
#define CHS2 (WIN*WROW)    // 600 floats per channel
#define CB2 16             // channels per stage

// tw layout: tw[((r*9 + k)*CIN + c)*COUT + o]
__global__ void build_tw_kernel(const float* __restrict__ weight, float* __restrict__ tw) {
    int idx = blockIdx.x * blockDim.x + threadIdx.x;
    if (idx >= COUT * CIN) return;
    int o = idx / CIN, c = idx % CIN;
    float b[9];
#pragma unroll
    for (int t = 0; t < 9; ++t) b[t] = weight[(o * CIN + c) * 9 + t];

    float w45[9];
    const float cs = 0.70710678f;
#pragma unroll
    for (int i = 0; i < 3; ++i) {
#pragma unroll
        for (int j = 0; j < 3; ++j) {
            float ys = cs * (float)(i - 1) + cs * (float)(j - 1) + 1.0f;
            float xs = -cs * (float)(i - 1) + cs * (float)(j - 1) + 1.0f;
            float y0f = floorf(ys), x0f = floorf(xs);
            float wy = ys - y0f, wx = xs - x0f;
            int iy0 = (int)y0f, ix0 = (int)x0f;
            float a = 0.0f;
#pragma unroll
            for (int dy = 0; dy < 2; ++dy) {
#pragma unroll
                for (int dx = 0; dx < 2; ++dx) {
                    int iy = iy0 + dy, ix = ix0 + dx;
                    float wgt = (dy ? wy : 1.0f - wy) * (dx ? wx : 1.0f - wx);
                    bool valid = (iy >= 0) && (iy < 3) && (ix >= 0) && (ix < 3);
                    int iyc = min(max(iy, 0), 2), ixc = min(max(ix, 0), 2);
                    a += b[iyc * 3 + ixc] * (valid ? wgt : 0.0f);
                }
            }
            w45[i * 3 + j] = a;
        }
    }

#pragma unroll
    for (int r = 0; r < NORI; ++r) {
        const float* src = (r < 4) ? b : w45;
        int rr = r & 3;
#pragma unroll
        for (int i = 0; i < 3; ++i) {
#pragma unroll
            for (int j = 0; j < 3; ++j) {
                int si, sj;
                if (rr == 0) { si = i;     sj = j;     }
                else if (rr == 1) { si = j;     sj = 2 - i; }
                else if (rr == 2) { si = 2 - i; sj = 2 - j; }
                else { si = 2 - j; sj = i;     }
                tw[(((r * 9) + (i * 3 + j)) * CIN + c) * COUT + o] = src[si * 3 + sj];
            }
        }
    }
}

// K1: 3x3 conv 32ch -> 18 offset + 9 mask channels, fixups+sigmoid applied,
// planar output om[27][HW] in workspace.
__global__ __launch_bounds__(256, 4) void offset_mask_kernel(
    const float* __restrict__ x,
    const float* __restrict__ offw, const float* __restrict__ offb,
    const float* __restrict__ mskw, const float* __restrict__ mskb,
    float* __restrict__ om)
{
    __shared__ float L[CB1 * CHS1];

    const int tiles_x = IMG / TS;
    int bid = (int)blockIdx.x;
    // XCD band swizzle (1024 % 8 == 0 -> bijective)
    bid = (bid % 8) * (1024 / 8) + bid / 8;
    int bx = bid % tiles_x, by = bid / tiles_x;
    int tx = threadIdx.x & 15, ty = threadIdx.x >> 4;
    int X = bx * TS + tx, Y = by * TS + ty;
    int p = Y * IMG + X;
    int y0w = by * TS - 1, x0w = bx * TS - 1;

    float acc[27];
#pragma unroll
    for (int i = 0; i < 18; ++i) acc[i] = offb[i];
#pragma unroll
    for (int i = 0; i < 9; ++i) acc[18 + i] = mskb[i];

    for (int cb = 0; cb < CIN / CB1; ++cb) {
        __syncthreads();
        for (int i = threadIdx.x; i < CB1 * W1 * W1; i += 256) {
            int ch = i / (W1 * W1), cell = i % (W1 * W1);
            int rr = cell / W1, cc = cell % W1;
            int gy = y0w + rr, gx = x0w + cc;
            float v = 0.0f;
            if ((unsigned)gy < (unsigned)IMG && (unsigned)gx < (unsigned)IMG)
                v = x[(cb * CB1 + ch) * HW + gy * IMG + gx];
            L[ch * CHS1 + rr * WR1 + cc] = v;
        }
        __syncthreads();

        for (int ch = 0; ch < CB1; ++ch) {
            int c = cb * CB1 + ch;
            int base = ch * CHS1 + ty * WR1 + tx;
            float v[9];
#pragma unroll
            for (int j = 0; j < 3; ++j) {
                v[j * 3 + 0] = L[base + j * WR1 + 0];
                v[j * 3 + 1] = L[base + j * WR1 + 1];
                v[j * 3 + 2] = L[base + j * WR1 + 2];
            }
            const float* wo = offw + c * 9;   // wave-uniform
#pragma unroll
            for (int oc = 0; oc < 18; ++oc)
#pragma unroll
                for (int t = 0; t < 9; ++t)
                    acc[oc] = fmaf(v[t], wo[oc * CIN * 9 + t], acc[oc]);
            const float* wm = mskw + c * 9;
#pragma unroll
            for (int oc = 0; oc < 9; ++oc)
#pragma unroll
                for (int t = 0; t < 9; ++t)
                    acc[18 + oc] = fmaf(v[t], wm[oc * CIN * 9 + t], acc[18 + oc]);
        }
    }

    // fixups: offset ch 8,9 -> 0 ; mask ch4 logit -> 0 (sigmoid -> 0.5)
    acc[8] = 0.0f; acc[9] = 0.0f; acc[22] = 0.0f;
#pragma unroll
    for (int oc = 0; oc < 18; ++oc) om[oc * HW + p] = acc[oc];
#pragma unroll
    for (int mk = 0; mk < 9; ++mk)
        om[(18 + mk) * HW + p] = 1.0f / (1.0f + __expf(-acc[18 + mk]));
}

// K2: deformable sampling + per-pixel GEMV against tw[sector] + relu.
// Runtime k-loop; per-tap offsets loaded from om[] (no runtime-indexed
// register arrays -> no scratch; only oacc[32] statically indexed persists).
__global__ __launch_bounds__(256, 2) void deform_gemv_kernel(
    const float* __restrict__ x,
    const float* __restrict__ om,
    const float* __restrict__ gm,
    const float* __restrict__ tw,
    float* __restrict__ out)
{
    __shared__ float L[CB2 * CHS2];

    const int tiles_x = IMG / TS;
    int bid = (int)blockIdx.x;
    bid = (bid % 8) * (1024 / 8) + bid / 8;
    int bx = bid % tiles_x, by = bid / tiles_x;
    int tx = threadIdx.x & 15, ty = threadIdx.x >> 4;
    int X = bx * TS + tx, Y = by * TS + ty;
    int p = Y * IMG + X;
    int y0w = by * TS - HALO, x0w = bx * TS - HALO;

    // sector from one-hot group_mask
    int r = 0;
#pragma unroll
    for (int n = 1; n < NORI; ++n) r = (gm[n * HW + p] > 0.5f) ? n : r;

    float oacc[32];
#pragma unroll
    for (int o = 0; o < 32; ++o) oacc[o] = 0.0f;

    for (int cb = 0; cb < CIN / CB2; ++cb) {
        __syncthreads();
        for (int i = threadIdx.x; i < CB2 * WIN * WIN; i += 256) {
            int ch = i / (WIN * WIN), cell = i % (WIN * WIN);
            int rr = cell / WIN, cc = cell % WIN;
            int gy = y0w + rr, gx = x0w + cc;
            float v = 0.0f;
            if ((unsigned)gy < (unsigned)IMG && (unsigned)gx < (unsigned)IMG)
                v = x[(cb * CB2 + ch) * HW + gy * IMG + gx];
            L[ch * CHS2 + rr * WROW + cc] = v;
        }
        __syncthreads();

        for (int k = 0; k < 9; ++k) {   // runtime loop: small body, no arrays
            int ky = k / 3, kx = k - ky * 3;
            float offy = om[(2 * k) * HW + p];
            float offx = om[(2 * k + 1) * HW + p];
            float m    = om[(18 + k) * HW + p];
            float pyf = (float)(Y - 1 + ky) + offy;
            float pxf = (float)(X - 1 + kx) + offx;
            float y0f = floorf(pyf), x0f = floorf(pxf);
            float wy = pyf - y0f, wx = pxf - x0f;
            int iy0 = (int)y0f, ix0 = (int)x0f;
            int iy1 = iy0 + 1, ix1 = ix0 + 1;
            float vy0 = ((unsigned)iy0 < (unsigned)IMG) ? 1.0f : 0.0f;
            float vy1 = ((unsigned)iy1 < (unsigned)IMG) ? 1.0f : 0.0f;
            float vx0 = ((unsigned)ix0 < (unsigned)IMG) ? 1.0f : 0.0f;
            float vx1 = ((unsigned)ix1 < (unsigned)IMG) ? 1.0f : 0.0f;
            int cy0 = min(max(iy0, 0), IMG - 1), cy1 = min(max(iy1, 0), IMG - 1);
            int cx0 = min(max(ix0, 0), IMG - 1), cx1 = min(max(ix1, 0), IMG - 1);
            float w00 = m * (1.0f - wy) * (1.0f - wx) * vy0 * vx0;
            float w01 = m * (1.0f - wy) * wx * vy0 * vx1;
            float w10 = m * wy * (1.0f - wx) * vy1 * vx0;
            float w11 = m * wy * wx * vy1 * vx1;

            int ry0 = cy0 - y0w, rx0 = cx0 - x0w;
            int ry1 = cy1 - y0w, rx1 = cx1 - x0w;
            bool inwin = ((unsigned)ry0 < WIN) && ((unsigned)rx0 < WIN) &&
                         ((unsigned)ry1 < WIN) && ((unsigned)rx1 < WIN);
            const float* twk = tw + ((r * 9 + k) * CIN + cb * CB2) * COUT;

            if (__all(inwin)) {
                // each corner indexed by its own clamped coords (R3 fix)
                int l00 = ry0 * WROW + rx0, l01 = ry0 * WROW + rx1;
                int l10 = ry1 * WROW + rx0, l11 = ry1 * WROW + rx1;
                for (int ch = 0; ch < CB2; ++ch) {
                    int lb = ch * CHS2;
                    float s = fmaf(w00, L[lb + l00], fmaf(w01, L[lb + l01],
                              fmaf(w10, L[lb + l10], w11 * L[lb + l11])));
                    const float4* t4p = (const float4*)(twk + ch * COUT);
#pragma unroll
                    for (int oq = 0; oq < 8; ++oq) {
                        float4 t4 = t4p[oq];
                        oacc[oq * 4 + 0] = fmaf(s, t4.x, oacc[oq * 4 + 0]);
                        oacc[oq * 4 + 1] = fmaf(s, t4.y, oacc[oq * 4 + 1]);
                        oacc[oq * 4 + 2] = fmaf(s, t4.z, oacc[oq * 4 + 2]);
                        oacc[oq * 4 + 3] = fmaf(s, t4.w, oacc[oq * 4 + 3]);
                    }
                }
            } else {
                int g00 = cy0 * IMG + cx0, g01 = cy0 * IMG + cx1;
                int g10 = cy1 * IMG + cx0, g11 = cy1 * IMG + cx1;
                for (int ch = 0; ch < CB2; ++ch) {
                    const float* xc = x + (cb * CB2 + ch) * HW;
                    float s = fmaf(w00, xc[g00], fmaf(w01, xc[g01],
                              fmaf(w10, xc[g10], w11 * xc[g11])));
                    const float4* t4p = (const float4*)(twk + ch * COUT);
#pragma unroll
                    for (int oq = 0; oq < 8; ++oq) {
                        float4 t4 = t4p[oq];
                        oacc[oq * 4 + 0] = fmaf(s, t4.x, oacc[oq * 4 + 0]);
                        oacc[oq * 4 + 1] = fmaf(s, t4.y, oacc[oq * 4 + 1]);
                        oacc[oq * 4 + 2] = fmaf(s, t4.z, oacc[oq * 4 + 2]);
                        oacc[oq * 4 + 3] = fmaf(s, t4.w, oacc[oq * 4 + 3]);
                    }
                }
            }
        }
    }

#pragma unroll
    for (int o = 0; o < 32; ++o) out[o * HW + p] = fmaxf(oacc[o], 0.0f);
}

extern "C" void kernel_launch(void* const* d_in, const int* in_sizes, int n_in,
                              void* d_out, int out_size, void* d_ws, size_t ws_size,
                              hipStream_t stream) {
    const float* x      = (const float*)d_in[0];
    const float* weight = (const float*)d_in[1];
    const float* offw   = (const float*)d_in[2];
    const float* offb   = (const float*)d_in[3];
    const float* mskw   = (const float*)d_in[4];
    const float* mskb   = (const float*)d_in[5];
    const float* gm     = (const float*)d_in[6];
    float* out = (float*)d_out;

    float* tw = (float*)d_ws;                       // 294912 B
    float* om = (float*)((char*)d_ws + 294912);     // 27*HW*4 = 28.3 MB

    build_tw_kernel<<<4, 256, 0, stream>>>(weight, tw);

    const int tiles = (IMG / TS) * (IMG / TS); // 1024
    offset_mask_kernel<<<tiles, 256, 0, stream>>>(x, offw, offb, mskw, mskb, om);
    deform_gemv_kernel<<<tiles, 256, 0, stream>>>(x, om, gm, tw, out);
}